// Round 2
// baseline (1260.237 us; speedup 1.0000x reference)
//
#include <hip/hip_runtime.h>
#include <hip/hip_bf16.h>

// Problem dims (fixed by setup_inputs):
//   N=64, C=192, T=64, V=25, H=6, d=32, B=N*V=1600
#define N_ 64
#define C_ 192
#define T_ 64
#define V_ 25
#define H_ 6
#define D_ 32
#define B_ 1600   // N_*V_

// ---------------------------------------------------------------------------
// Kernel 1: transpose x (N,C,T,V) -> xr (B=N*V, C, T)
// ---------------------------------------------------------------------------
__global__ __launch_bounds__(256) void k_transpose(const float* __restrict__ x,
                                                   float* __restrict__ xr) {
    int n = blockIdx.x / C_;
    int c = blockIdx.x % C_;
    const float* src = x + ((size_t)n * C_ + c) * (T_ * V_);  // (t,v) row-major
    __shared__ float tile[T_ * V_];
    for (int i = threadIdx.x; i < T_ * V_; i += 256) tile[i] = src[i];
    __syncthreads();
    for (int i = threadIdx.x; i < T_ * V_; i += 256) {
        int v = i / T_;
        int t = i % T_;
        xr[((size_t)(n * V_ + v) * C_ + c) * T_ + t] = tile[t * V_ + v];
    }
}

// ---------------------------------------------------------------------------
// Kernel 2: QKV GEMM  qkv[b] = w_qkv(576x192) @ xr[b](192x64) + b_qkv
// ---------------------------------------------------------------------------
__global__ __launch_bounds__(256) void k_qkv_gemm(const float* __restrict__ W,
                                                  const float* __restrict__ bias,
                                                  const float* __restrict__ X,
                                                  float* __restrict__ Y) {
    int bid = blockIdx.x;
    int b  = bid / 9;
    int mo = bid % 9;
    const float* Xb = X + (size_t)b * C_ * T_;
    float* Yb = Y + (size_t)b * (3 * C_) * T_;

    __shared__ float As[64][33];
    __shared__ float Bs[32][64];

    int tid = threadIdx.x;
    int tx = tid & 15;
    int ty = tid >> 4;
    float acc[4][4] = {};

    for (int k0 = 0; k0 < C_; k0 += 32) {
        for (int i = tid; i < 64 * 32; i += 256) {
            int m = i >> 5, kk = i & 31;
            As[m][kk] = W[(size_t)(mo * 64 + m) * C_ + k0 + kk];
        }
        for (int i = tid; i < 32 * 64; i += 256) {
            int kk = i >> 6, t = i & 63;
            Bs[kk][t] = Xb[(size_t)(k0 + kk) * T_ + t];
        }
        __syncthreads();
        for (int kk = 0; kk < 32; ++kk) {
            float a[4], bb[4];
#pragma unroll
            for (int i = 0; i < 4; ++i) a[i] = As[ty * 4 + i][kk];
#pragma unroll
            for (int j = 0; j < 4; ++j) bb[j] = Bs[kk][tx * 4 + j];
#pragma unroll
            for (int i = 0; i < 4; ++i)
#pragma unroll
                for (int j = 0; j < 4; ++j) acc[i][j] += a[i] * bb[j];
        }
        __syncthreads();
    }
#pragma unroll
    for (int i = 0; i < 4; ++i) {
        int o = mo * 64 + ty * 4 + i;
        float bv = bias[o];
#pragma unroll
        for (int j = 0; j < 4; ++j)
            Yb[(size_t)o * T_ + tx * 4 + j] = acc[i][j] + bv;
    }
}

// ---------------------------------------------------------------------------
// Kernel 3: fused attention per (b,h).  Bank-conflict-free version:
//   - rk padded to stride 33 (was 32-way conflict -> <=2-way)
//   - wt[][] eliminated: partial PV in registers + __shfl_xor quad reduce
//   - ao padded to stride 33
//   - q hoisted to 32 registers; float4 staging loads
// LDS: 3*8KB + 16.4KB + 8.25KB = 49.8KB -> 3 blocks/CU
// ---------------------------------------------------------------------------
__global__ __launch_bounds__(256) void k_attn(const float* __restrict__ qkv,
                                              const float* __restrict__ rel_emb,
                                              float* __restrict__ attnR) {
    int bid = blockIdx.x;                   // B*H
    int b = bid / H_;
    int h = bid % H_;
    const float* base = qkv + (size_t)b * (3 * C_) * T_;

    __shared__ float qs[D_][T_];
    __shared__ float ks[D_][T_];
    __shared__ float vs[D_][T_];
    __shared__ float rk[2 * T_ - 1][D_ + 1];   // pad -> stride 33
    __shared__ float ao[T_][D_ + 1];           // pad -> stride 33

    int tid = threadIdx.x;
    const float4* qsrc = (const float4*)(base + (size_t)(h * D_) * T_);
    const float4* ksrc = (const float4*)(base + (size_t)(C_ + h * D_) * T_);
    const float4* vsrc = (const float4*)(base + (size_t)(2 * C_ + h * D_) * T_);
    for (int i = tid; i < D_ * T_ / 4; i += 256) {
        ((float4*)qs)[i] = qsrc[i];
        ((float4*)ks)[i] = ksrc[i];
        ((float4*)vs)[i] = vsrc[i];
    }
    for (int i = tid; i < (2 * T_ - 1) * D_ / 4; i += 256) {
        float4 r = ((const float4*)rel_emb)[i];
        int m = i >> 3;
        int d4 = (i & 7) * 4;
        rk[m][d4 + 0] = r.x;
        rk[m][d4 + 1] = r.y;
        rk[m][d4 + 2] = r.z;
        rk[m][d4 + 3] = r.w;
    }
    __syncthreads();

    int t = tid >> 2;
    int quad = tid & 3;

    float qreg[D_];
#pragma unroll
    for (int dd = 0; dd < D_; ++dd) qreg[dd] = qs[dd][t];

    // logits for 16 s-values (s = quad*16+si)
    float vals[16];
    float mx = -INFINITY;
#pragma unroll
    for (int si = 0; si < 16; ++si) {
        int s = quad * 16 + si;
        int m = s - t + (T_ - 1);
        float acc = 0.f;
#pragma unroll
        for (int dd = 0; dd < D_; ++dd) {
            acc += qreg[dd] * ks[dd][s];
            acc += qreg[dd] * rk[m][dd];
        }
        vals[si] = acc;
        mx = fmaxf(mx, acc);
    }
    mx = fmaxf(mx, __shfl_xor(mx, 1));
    mx = fmaxf(mx, __shfl_xor(mx, 2));
    float sum = 0.f;
#pragma unroll
    for (int si = 0; si < 16; ++si) {
        vals[si] = __expf(vals[si] - mx);
        sum += vals[si];
    }
    sum += __shfl_xor(sum, 1);
    sum += __shfl_xor(sum, 2);
    float inv = 1.0f / sum;

    // partial PV over own 16 s-values, all 32 dd, then quad-reduce via shfl
    float pacc[D_];
#pragma unroll
    for (int dd = 0; dd < D_; ++dd) pacc[dd] = 0.f;
#pragma unroll
    for (int si = 0; si < 16; ++si) {
        int s = quad * 16 + si;
        float w = vals[si];
#pragma unroll
        for (int dd = 0; dd < D_; ++dd) pacc[dd] += w * vs[dd][s];
    }
#pragma unroll
    for (int dd = 0; dd < D_; ++dd) {
        pacc[dd] += __shfl_xor(pacc[dd], 1);
        pacc[dd] += __shfl_xor(pacc[dd], 2);
    }
    // each quad writes 8 of the 32 dd (all quads hold full sums)
#pragma unroll
    for (int u = 0; u < 8; ++u) {
        int dd = quad * 8 + u;
        ao[t][dd] = pacc[dd] * inv;
    }
    __syncthreads();

    // scrambled write (reference reshape(B,H,d,1,T).transpose(0,1,3,4,2))
    float* dst = attnR + ((size_t)b * C_ + h * D_) * T_;
    for (int i = tid; i < D_ * T_; i += 256) {
        int qr = i >> 6;                    // c%32
        int tout = i & 63;
        int ii = tout & 31;
        int j = 2 * qr + (tout >> 5);
        int tA = 2 * ii + (j >> 5);
        int dA = j & 31;
        dst[i] = ao[tA][dA];
    }
}

// ---------------------------------------------------------------------------
// Kernel 4: output GEMM  out[b] = w_out(192x192) @ attnR[b](192x64) + b_out
// ---------------------------------------------------------------------------
__global__ __launch_bounds__(256) void k_out_gemm(const float* __restrict__ W,
                                                  const float* __restrict__ bias,
                                                  const float* __restrict__ X,
                                                  float* __restrict__ out) {
    int bid = blockIdx.x;
    int b  = bid / 3;
    int mo = bid % 3;
    const float* Xb = X + (size_t)b * C_ * T_;

    __shared__ float As[64][33];
    __shared__ float Bs[32][64];

    int tid = threadIdx.x;
    int tx = tid & 15;
    int ty = tid >> 4;
    float acc[4][4] = {};

    for (int k0 = 0; k0 < C_; k0 += 32) {
        for (int i = tid; i < 64 * 32; i += 256) {
            int m = i >> 5, kk = i & 31;
            As[m][kk] = W[(size_t)(mo * 64 + m) * C_ + k0 + kk];
        }
        for (int i = tid; i < 32 * 64; i += 256) {
            int kk = i >> 6, t = i & 63;
            Bs[kk][t] = Xb[(size_t)(k0 + kk) * T_ + t];
        }
        __syncthreads();
        for (int kk = 0; kk < 32; ++kk) {
            float a[4], bb[4];
#pragma unroll
            for (int i = 0; i < 4; ++i) a[i] = As[ty * 4 + i][kk];
#pragma unroll
            for (int j = 0; j < 4; ++j) bb[j] = Bs[kk][tx * 4 + j];
#pragma unroll
            for (int i = 0; i < 4; ++i)
#pragma unroll
                for (int j = 0; j < 4; ++j) acc[i][j] += a[i] * bb[j];
        }
        __syncthreads();
    }

    int n = b / V_;
    int v = b % V_;
#pragma unroll
    for (int i = 0; i < 4; ++i) {
        int o = mo * 64 + ty * 4 + i;
        float bv = bias[o];
#pragma unroll
        for (int j = 0; j < 4; ++j) {
            int tcol = tx * 4 + j;
            out[((size_t)n * C_ + o) * (T_ * V_) + (size_t)tcol * V_ + v] =
                acc[i][j] + bv;
        }
    }
}

// ---------------------------------------------------------------------------
extern "C" void kernel_launch(void* const* d_in, const int* in_sizes, int n_in,
                              void* d_out, int out_size, void* d_ws, size_t ws_size,
                              hipStream_t stream) {
    const float* x       = (const float*)d_in[0];
    const float* w_qkv   = (const float*)d_in[1];
    const float* b_qkv   = (const float*)d_in[2];
    const float* w_out   = (const float*)d_in[3];
    const float* b_out   = (const float*)d_in[4];
    const float* rel_emb = (const float*)d_in[5];
    float* out = (float*)d_out;

    float* xr    = (float*)d_ws;
    float* qkv   = xr + (size_t)B_ * C_ * T_;
    float* attnR = xr;  // reuse: xr dead after QKV GEMM

    k_transpose<<<N_ * C_, 256, 0, stream>>>(x, xr);
    k_qkv_gemm<<<B_ * 9, 256, 0, stream>>>(w_qkv, b_qkv, xr, qkv);
    k_attn<<<B_ * H_, 256, 0, stream>>>(qkv, rel_emb, attnR);
    k_out_gemm<<<B_ * 3, 256, 0, stream>>>(w_out, b_out, attnR, out);
}

// Round 3
// 230.468 us; speedup vs baseline: 5.4682x; 5.4682x over previous
//
#include <hip/hip_runtime.h>
#include <hip/hip_bf16.h>
#include <hip/hip_fp16.h>
#include <stdint.h>

// Problem dims (fixed): N=64, C=192, T=64, V=25, H=6, d=32, B=N*V=1600
#define N_ 64
#define C_ 192
#define T_ 64
#define V_ 25
#define H_ 6
#define D_ 32
#define B_ 1600

typedef __attribute__((ext_vector_type(8))) short s16x8;
typedef __attribute__((ext_vector_type(4))) float f32x4;

__device__ __forceinline__ unsigned short f2bf(float f) {
    union { float f; uint32_t u; } v; v.f = f;
    uint32_t r = v.u + 0x7FFFu + ((v.u >> 16) & 1u);   // RNE
    return (unsigned short)(r >> 16);
}

// ---------------------------------------------------------------------------
// Kernel 0: convert weights to bf16 (w_qkv 576x192, w_out 192x192)
// ---------------------------------------------------------------------------
__global__ __launch_bounds__(256) void k_wconv(const float* __restrict__ wq,
                                               const float* __restrict__ wo,
                                               unsigned short* __restrict__ wqb,
                                               unsigned short* __restrict__ wob) {
    int i = blockIdx.x * 256 + threadIdx.x;
    const int NQ = 3 * C_ * C_;       // 110592
    const int NO = C_ * C_;           // 36864
    if (i < NQ) wqb[i] = f2bf(wq[i]);
    else if (i < NQ + NO) wob[i - NQ] = f2bf(wo[i - NQ]);
}

// ---------------------------------------------------------------------------
// Kernel 1: x (N,C,T,V) fp32 -> xt[(n*V+v)][t][c] bf16
// grid = N * 6 cgroups * 2 ihalves = 768 blocks
// ---------------------------------------------------------------------------
__global__ __launch_bounds__(256) void k_xpose(const float* __restrict__ x,
                                               unsigned short* __restrict__ xt) {
    int bid = blockIdx.x;
    int n = bid / 12, r = bid % 12, cg = r >> 1, ih = r & 1;
    __shared__ unsigned short tile[800][40];   // 64000 B
    int tid = threadIdx.x;
    {
        int cc = tid >> 3, part = tid & 7;     // cc 0..31, 100 elems each
        const float4* src = (const float4*)(x + ((size_t)n * C_ + cg * 32 + cc) * 1600
                                              + ih * 800 + part * 100);
#pragma unroll
        for (int u = 0; u < 25; ++u) {
            float4 f = src[u];
            int i = part * 100 + u * 4;
            tile[i + 0][cc] = f2bf(f.x);
            tile[i + 1][cc] = f2bf(f.y);
            tile[i + 2][cc] = f2bf(f.z);
            tile[i + 3][cc] = f2bf(f.w);
        }
    }
    __syncthreads();
    for (int i = tid; i < 800; i += 256) {
        int gi = ih * 800 + i;
        int t = (gi * 5243) >> 17;             // gi/25 (exact for gi<1600)
        int v = gi - t * 25;
        unsigned short* dst = xt + (((size_t)(n * V_ + v) * T_) + t) * C_ + cg * 32;
        const s16x8* srow = (const s16x8*)&tile[i][0];
        ((s16x8*)dst)[0] = srow[0];
        ((s16x8*)dst)[1] = srow[1];
        ((s16x8*)dst)[2] = srow[2];
        ((s16x8*)dst)[3] = srow[3];
    }
}

// ---------------------------------------------------------------------------
// Kernel 2: QKV GEMM (bf16 MFMA): qkv[b][o][t] = sum_c Wb[o][c]*xt[b][t][c] + bias
// grid = B*9; block 256 = 4 waves; wave = 16-row strip of the 64x64 tile
// ---------------------------------------------------------------------------
__global__ __launch_bounds__(256) void k_qkv(const unsigned short* __restrict__ Wb,
                                             const float* __restrict__ bias,
                                             const unsigned short* __restrict__ xt,
                                             unsigned short* __restrict__ qkv) {
    int bid = blockIdx.x;
    int b = bid / 9, mo = bid % 9;
    __shared__ unsigned short Bs[64][200];     // [t][c], stride 200 (400B, 16-al)
    int tid = threadIdx.x;
    {
        int t = tid >> 2, q = tid & 3;
        const s16x8* src = (const s16x8*)(xt + ((size_t)b * T_ + t) * C_ + q * 48);
        s16x8* dst = (s16x8*)&Bs[t][q * 48];
        dst[0] = src[0]; dst[1] = src[1]; dst[2] = src[2];
        dst[3] = src[3]; dst[4] = src[4]; dst[5] = src[5];
    }
    __syncthreads();
    int wave = tid >> 6, lane = tid & 63;
    int lr = lane & 15, lg = lane >> 4;

    f32x4 acc[4];
#pragma unroll
    for (int nt = 0; nt < 4; ++nt) acc[nt] = (f32x4){0.f, 0.f, 0.f, 0.f};

    const unsigned short* arow = Wb + (size_t)(mo * 64 + wave * 16 + lr) * C_ + lg * 8;
#pragma unroll
    for (int k0 = 0; k0 < C_; k0 += 32) {
        s16x8 a = *(const s16x8*)(arow + k0);
#pragma unroll
        for (int nt = 0; nt < 4; ++nt) {
            s16x8 bf = *(const s16x8*)&Bs[nt * 16 + lr][k0 + lg * 8];
            acc[nt] = __builtin_amdgcn_mfma_f32_16x16x32_bf16(a, bf, acc[nt], 0, 0, 0);
        }
    }
    size_t obase = (size_t)b * (3 * C_) * T_;
#pragma unroll
    for (int nt = 0; nt < 4; ++nt) {
#pragma unroll
        for (int r2 = 0; r2 < 4; ++r2) {
            int o = mo * 64 + wave * 16 + lg * 4 + r2;
            int t = nt * 16 + lr;
            qkv[obase + (size_t)o * T_ + t] = f2bf(acc[nt][r2] + bias[o]);
        }
    }
}

// ---------------------------------------------------------------------------
// Kernel 3: fused attention per (b,h), bf16 MFMA.
//   logits = Q^T K + rel_to_abs(Q^T rel^T); softmax fp32; attn = W V^T
//   writes aT[b][t][h*32+qr] with the reference reshape-scramble applied
// ---------------------------------------------------------------------------
__global__ __launch_bounds__(256) void k_attn(const unsigned short* __restrict__ qkv,
                                              const float* __restrict__ rel_emb,
                                              unsigned short* __restrict__ aT) {
    int bid = blockIdx.x;
    int b = bid / H_, h = bid % H_;
    __shared__ unsigned short qt[64][40];      // [t][d] swizzled d-blocks
    __shared__ unsigned short kt[64][40];      // [s][d] swizzled
    __shared__ unsigned short vsm[32][72];     // [d][s]
    __shared__ unsigned short rel[128][40];    // [m][d], row127 = 0
    __shared__ unsigned short wls[64][72];     // softmax weights [t][s]
    __shared__ __half rel_l[64][132];          // rel_logits [t][m]; ao aliased
    unsigned short (*ao)[40] = (unsigned short(*)[40])&rel_l[0][0];

    int tid = threadIdx.x;
    const unsigned short* base = qkv + (size_t)b * (3 * C_) * T_;
    {
        int d = tid >> 3, tg = tid & 7;
        s16x8 qv = *(const s16x8*)(base + (size_t)(h * D_ + d) * T_ + tg * 8);
        s16x8 kv = *(const s16x8*)(base + (size_t)(C_ + h * D_ + d) * T_ + tg * 8);
        s16x8 vv = *(const s16x8*)(base + (size_t)(2 * C_ + h * D_ + d) * T_ + tg * 8);
#pragma unroll
        for (int j = 0; j < 8; ++j) {
            int t = tg * 8 + j;
            int col = (d & 7) | ((((d >> 3) ^ ((t >> 3) & 3)) & 3) << 3);
            qt[t][col] = (unsigned short)qv[j];
            kt[t][col] = (unsigned short)kv[j];
        }
        *(s16x8*)&vsm[d][tg * 8] = vv;
    }
    {
        int m = tid >> 1, hf = tid & 1;
        unsigned short tmp[16];
        if (m < 127) {
            const float4* rsrc = (const float4*)(rel_emb + (size_t)m * D_ + hf * 16);
#pragma unroll
            for (int u = 0; u < 4; ++u) {
                float4 f = rsrc[u];
                tmp[u * 4 + 0] = f2bf(f.x); tmp[u * 4 + 1] = f2bf(f.y);
                tmp[u * 4 + 2] = f2bf(f.z); tmp[u * 4 + 3] = f2bf(f.w);
            }
        } else {
#pragma unroll
            for (int u = 0; u < 16; ++u) tmp[u] = 0;
        }
        s16x8* dst = (s16x8*)&rel[m][hf * 16];
        dst[0] = *(s16x8*)&tmp[0];
        dst[1] = *(s16x8*)&tmp[8];
    }
    __syncthreads();

    int wave = tid >> 6, lane = tid & 63;
    int lr = lane & 15, lg = lane >> 4;
    int t0 = wave * 16;
    int tA = t0 + lr;
    s16x8 afq = *(const s16x8*)&qt[tA][((lg ^ ((tA >> 3) & 3)) & 3) << 3];

    // QK^T: 4 N-tiles over s
    f32x4 accS[4];
#pragma unroll
    for (int nt = 0; nt < 4; ++nt) {
        int s = nt * 16 + lr;
        s16x8 bf = *(const s16x8*)&kt[s][((lg ^ ((s >> 3) & 3)) & 3) << 3];
        f32x4 z = (f32x4){0.f, 0.f, 0.f, 0.f};
        accS[nt] = __builtin_amdgcn_mfma_f32_16x16x32_bf16(afq, bf, z, 0, 0, 0);
    }
    // rel logits: 8 N-tiles over m -> rel_l (fp16)
#pragma unroll
    for (int mt = 0; mt < 8; ++mt) {
        int m = mt * 16 + lr;
        s16x8 bf = *(const s16x8*)&rel[m][lg * 8];
        f32x4 z = (f32x4){0.f, 0.f, 0.f, 0.f};
        f32x4 rr = __builtin_amdgcn_mfma_f32_16x16x32_bf16(afq, bf, z, 0, 0, 0);
#pragma unroll
        for (int r2 = 0; r2 < 4; ++r2)
            rel_l[t0 + lg * 4 + r2][mt * 16 + lr] = __float2half(rr[r2]);
    }
    __syncthreads();

    // softmax (fp32): lane owns 4 rows (t0+lg*4+r2) x 4 cols (nt*16+lr)
    float vals[4][4], mx[4], inv[4];
#pragma unroll
    for (int r2 = 0; r2 < 4; ++r2) {
        int t = t0 + lg * 4 + r2;
        float m0 = -1e30f;
#pragma unroll
        for (int nt = 0; nt < 4; ++nt) {
            int s = nt * 16 + lr;
            float v = accS[nt][r2] + __half2float(rel_l[t][s - t + 63]);
            vals[nt][r2] = v;
            m0 = fmaxf(m0, v);
        }
        m0 = fmaxf(m0, __shfl_xor(m0, 1));
        m0 = fmaxf(m0, __shfl_xor(m0, 2));
        m0 = fmaxf(m0, __shfl_xor(m0, 4));
        m0 = fmaxf(m0, __shfl_xor(m0, 8));
        mx[r2] = m0;
    }
#pragma unroll
    for (int r2 = 0; r2 < 4; ++r2) {
        float s0 = 0.f;
#pragma unroll
        for (int nt = 0; nt < 4; ++nt) {
            float e = __expf(vals[nt][r2] - mx[r2]);
            vals[nt][r2] = e;
            s0 += e;
        }
        s0 += __shfl_xor(s0, 1);
        s0 += __shfl_xor(s0, 2);
        s0 += __shfl_xor(s0, 4);
        s0 += __shfl_xor(s0, 8);
        inv[r2] = 1.0f / s0;
    }
#pragma unroll
    for (int r2 = 0; r2 < 4; ++r2) {
        int t = t0 + lg * 4 + r2;
#pragma unroll
        for (int nt = 0; nt < 4; ++nt)
            wls[t][nt * 16 + lr] = f2bf(vals[nt][r2] * inv[r2]);
    }
    __syncthreads();   // wls ready; also fences rel_l reads before ao overwrite

    // PV: attn[t][dd] = sum_s w[t][s] * v[dd][s]
    f32x4 accO[2];
    accO[0] = (f32x4){0.f, 0.f, 0.f, 0.f};
    accO[1] = (f32x4){0.f, 0.f, 0.f, 0.f};
#pragma unroll
    for (int ks = 0; ks < 2; ++ks) {
        s16x8 pa = *(const s16x8*)&wls[tA][ks * 32 + lg * 8];
#pragma unroll
        for (int nt = 0; nt < 2; ++nt) {
            s16x8 bf = *(const s16x8*)&vsm[nt * 16 + lr][ks * 32 + lg * 8];
            accO[nt] = __builtin_amdgcn_mfma_f32_16x16x32_bf16(pa, bf, accO[nt], 0, 0, 0);
        }
    }
#pragma unroll
    for (int nt = 0; nt < 2; ++nt)
#pragma unroll
        for (int r2 = 0; r2 < 4; ++r2)
            ao[t0 + lg * 4 + r2][nt * 16 + lr] = f2bf(accO[nt][r2]);
    __syncthreads();

    // scrambled write: aT[b][tout][h*32+qr] = ao[tA][dA]
    unsigned short* dstb = aT + (size_t)b * T_ * C_ + h * D_;
#pragma unroll
    for (int it = 0; it < 8; ++it) {
        int idx = it * 256 + tid;
        int qr = idx & 31, tout = idx >> 5;
        int ii = tout & 31;
        int j = 2 * qr + (tout >> 5);
        int tAo = 2 * ii + (j >> 5);
        int dA = j & 31;
        dstb[(size_t)tout * C_ + qr] = ao[tAo][dA];
    }
}

// ---------------------------------------------------------------------------
// Kernel 4: out GEMM (bf16 MFMA), writes final (N,C,T,V) fp32 contiguously.
// grid = N * 3 mo * 4 tchunk = 768; block 256 = 4 waves (wave = 16-row Mtile)
// N-dim = 400 cols = (16 t) x (25 v), col = t_local*25+v
// ---------------------------------------------------------------------------
__global__ __launch_bounds__(256) void k_out(const unsigned short* __restrict__ Wb,
                                             const float* __restrict__ bias,
                                             const unsigned short* __restrict__ aT,
                                             float* __restrict__ out) {
    int bid = blockIdx.x;
    int n = bid / 12, r = bid % 12, mo = r >> 2, tc = r & 3;
    __shared__ unsigned short Bs[400][40];     // [col][k], 32KB
    int tid = threadIdx.x;
    int wave = tid >> 6, lane = tid & 63;
    int lr = lane & 15, lg = lane >> 4;

    f32x4 acc[25];
#pragma unroll
    for (int j = 0; j < 25; ++j) acc[j] = (f32x4){0.f, 0.f, 0.f, 0.f};

    const unsigned short* arow = Wb + (size_t)(mo * 64 + wave * 16 + lr) * C_ + lg * 8;

    for (int k0 = 0; k0 < C_; k0 += 32) {
        __syncthreads();
        for (int col = tid; col < 400; col += 256) {
            int tl = (col * 41) >> 10;         // col/25 (exact for col<624)
            int v = col - tl * 25;
            const s16x8* src = (const s16x8*)(aT +
                ((size_t)(n * V_ + v) * T_ + tc * 16 + tl) * C_ + k0);
            s16x8* dst = (s16x8*)&Bs[col][0];
            dst[0] = src[0]; dst[1] = src[1]; dst[2] = src[2]; dst[3] = src[3];
        }
        __syncthreads();
        s16x8 a = *(const s16x8*)(arow + k0);
#pragma unroll
        for (int j = 0; j < 25; ++j) {
            s16x8 bf = *(const s16x8*)&Bs[j * 16 + lr][lg * 8];
            acc[j] = __builtin_amdgcn_mfma_f32_16x16x32_bf16(a, bf, acc[j], 0, 0, 0);
        }
    }
#pragma unroll
    for (int j = 0; j < 25; ++j) {
        int c = j * 16 + lr;
        int tl = (c * 41) >> 10;
        int v = c - tl * 25;
        int t = tc * 16 + tl;
#pragma unroll
        for (int r2 = 0; r2 < 4; ++r2) {
            int o = mo * 64 + wave * 16 + lg * 4 + r2;
            out[(((size_t)n * C_ + o) * T_ + t) * V_ + v] = acc[j][r2] + bias[o];
        }
    }
}

// ---------------------------------------------------------------------------
extern "C" void kernel_launch(void* const* d_in, const int* in_sizes, int n_in,
                              void* d_out, int out_size, void* d_ws, size_t ws_size,
                              hipStream_t stream) {
    const float* x       = (const float*)d_in[0];
    const float* w_qkv   = (const float*)d_in[1];
    const float* b_qkv   = (const float*)d_in[2];
    const float* w_out   = (const float*)d_in[3];
    const float* b_out   = (const float*)d_in[4];
    const float* rel_emb = (const float*)d_in[5];
    float* out = (float*)d_out;

    // workspace (ushorts): xt | qkv | aT | wqb | wob   (~197 MB total)
    unsigned short* xt   = (unsigned short*)d_ws;
    unsigned short* qkvb = xt + (size_t)B_ * T_ * C_;
    unsigned short* aTb  = qkvb + (size_t)B_ * 3 * C_ * T_;
    unsigned short* wqb  = aTb + (size_t)B_ * T_ * C_;
    unsigned short* wob  = wqb + (size_t)3 * C_ * C_;

    k_wconv<<<576, 256, 0, stream>>>(w_qkv, w_out, wqb, wob);
    k_xpose<<<768, 256, 0, stream>>>(x, xt);
    k_qkv<<<B_ * 9, 256, 0, stream>>>(wqb, b_qkv, xt, qkvb);
    k_attn<<<B_ * H_, 256, 0, stream>>>(qkvb, rel_emb, aTb);
    k_out<<<768, 256, 0, stream>>>(wob, b_out, aTb, out);
}

// Round 5
// 207.852 us; speedup vs baseline: 6.0631x; 1.1088x over previous
//
#include <hip/hip_runtime.h>
#include <hip/hip_bf16.h>
#include <hip/hip_fp16.h>
#include <stdint.h>

// Problem dims (fixed): N=64, C=192, T=64, V=25, H=6, d=32, B=N*V=1600
#define N_ 64
#define C_ 192
#define T_ 64
#define V_ 25
#define H_ 6
#define D_ 32
#define B_ 1600
#define NQ_ (3 * C_ * C_)   // 110592
#define NO_ (C_ * C_)       // 36864

typedef __attribute__((ext_vector_type(8))) short s16x8;
typedef __attribute__((ext_vector_type(4))) float f32x4;

__device__ __forceinline__ unsigned short f2bf(float f) {
    union { float f; uint32_t u; } v; v.f = f;
    uint32_t r = v.u + 0x7FFFu + ((v.u >> 16) & 1u);   // RNE
    return (unsigned short)(r >> 16);
}

// ---------------------------------------------------------------------------
// Kernel 0: weights + rel_emb -> bf16 (relb padded to 128 rows, row127 = 0)
// ---------------------------------------------------------------------------
__global__ __launch_bounds__(256) void k_wconv(const float* __restrict__ wq,
                                               const float* __restrict__ wo,
                                               const float* __restrict__ rel_emb,
                                               unsigned short* __restrict__ wqb,
                                               unsigned short* __restrict__ wob,
                                               unsigned short* __restrict__ relb) {
    int i = blockIdx.x * 256 + threadIdx.x;
    if (i < NQ_) wqb[i] = f2bf(wq[i]);
    else if (i < NQ_ + NO_) wob[i - NQ_] = f2bf(wo[i - NQ_]);
    else {
        int j = i - (NQ_ + NO_);
        if (j < 128 * 32) {
            int m = j >> 5;
            relb[j] = (m < 127) ? f2bf(rel_emb[j]) : (unsigned short)0;
        }
    }
}

// ---------------------------------------------------------------------------
// Kernel 1: x (N,C,T,V) fp32 -> xt[(n*V+v)][t][c] bf16
// ---------------------------------------------------------------------------
__global__ __launch_bounds__(256) void k_xpose(const float* __restrict__ x,
                                               unsigned short* __restrict__ xt) {
    int bid = blockIdx.x;
    int n = bid / 12, r = bid % 12, cg = r >> 1, ih = r & 1;
    __shared__ unsigned short tile[800][40];   // 64000 B
    int tid = threadIdx.x;
    {
        int cc = tid >> 3, part = tid & 7;     // cc 0..31, 100 elems each
        const float4* src = (const float4*)(x + ((size_t)n * C_ + cg * 32 + cc) * 1600
                                              + ih * 800 + part * 100);
#pragma unroll
        for (int u = 0; u < 25; ++u) {
            float4 f = src[u];
            int i = part * 100 + u * 4;
            tile[i + 0][cc] = f2bf(f.x);
            tile[i + 1][cc] = f2bf(f.y);
            tile[i + 2][cc] = f2bf(f.z);
            tile[i + 3][cc] = f2bf(f.w);
        }
    }
    __syncthreads();
    for (int i = tid; i < 800; i += 256) {
        int gi = ih * 800 + i;
        int t = (gi * 5243) >> 17;             // gi/25 (exact for gi<1600)
        int v = gi - t * 25;
        unsigned short* dst = xt + (((size_t)(n * V_ + v) * T_) + t) * C_ + cg * 32;
        const s16x8* srow = (const s16x8*)&tile[i][0];
        ((s16x8*)dst)[0] = srow[0];
        ((s16x8*)dst)[1] = srow[1];
        ((s16x8*)dst)[2] = srow[2];
        ((s16x8*)dst)[3] = srow[3];
    }
}

// ---------------------------------------------------------------------------
// Kernel 2: QKV GEMM (bf16 MFMA): qkv[b][o][t] = sum_c Wb[o][c]*xt[b][t][c]+bias
// XCD-swizzled grid; epilogue bounces the 64x64 tile through LDS (aliased on
// Bs) then stores fully-coalesced 16 B/lane.
// ---------------------------------------------------------------------------
__global__ __launch_bounds__(256) void k_qkv(const unsigned short* __restrict__ Wb,
                                             const float* __restrict__ bias,
                                             const unsigned short* __restrict__ xt,
                                             unsigned short* __restrict__ qkv) {
    int virt = (blockIdx.x & 7) * (B_ * 9 / 8) + (blockIdx.x >> 3);
    int b = virt / 9, mo = virt % 9;
    __shared__ unsigned short Bs[64][200];     // [t][c], 25.6 KB
    int tid = threadIdx.x;
    {
        int t = tid >> 2, q = tid & 3;
        const s16x8* src = (const s16x8*)(xt + ((size_t)b * T_ + t) * C_ + q * 48);
        s16x8* dst = (s16x8*)&Bs[t][q * 48];
        dst[0] = src[0]; dst[1] = src[1]; dst[2] = src[2];
        dst[3] = src[3]; dst[4] = src[4]; dst[5] = src[5];
    }
    __syncthreads();
    int wave = tid >> 6, lane = tid & 63;
    int lr = lane & 15, lg = lane >> 4;

    f32x4 acc[4];
#pragma unroll
    for (int nt = 0; nt < 4; ++nt) acc[nt] = (f32x4){0.f, 0.f, 0.f, 0.f};

    const unsigned short* arow = Wb + (size_t)(mo * 64 + wave * 16 + lr) * C_ + lg * 8;
#pragma unroll
    for (int k0 = 0; k0 < C_; k0 += 32) {
        s16x8 a = *(const s16x8*)(arow + k0);
#pragma unroll
        for (int nt = 0; nt < 4; ++nt) {
            s16x8 bf = *(const s16x8*)&Bs[nt * 16 + lr][k0 + lg * 8];
            acc[nt] = __builtin_amdgcn_mfma_f32_16x16x32_bf16(a, bf, acc[nt], 0, 0, 0);
        }
    }
    __syncthreads();                           // all waves done reading Bs
    unsigned short (*Ls)[68] = (unsigned short (*)[68])&Bs[0][0];  // 8.7 KB alias
#pragma unroll
    for (int nt = 0; nt < 4; ++nt)
#pragma unroll
        for (int r2 = 0; r2 < 4; ++r2) {
            int ol = wave * 16 + lg * 4 + r2;
            Ls[ol][nt * 16 + lr] = f2bf(acc[nt][r2] + bias[mo * 64 + ol]);
        }
    __syncthreads();
    {
        int seg = tid & 7;                     // 8 ushorts each
#pragma unroll
        for (int half = 0; half < 2; ++half) {
            int o = (tid >> 3) + half * 32;
            *(s16x8*)(qkv + ((size_t)b * (3 * C_) + mo * 64 + o) * T_ + seg * 8) =
                *(const s16x8*)&Ls[o][seg * 8];
        }
    }
}

// ---------------------------------------------------------------------------
// Kernel 3: fused attention per (b,h), bf16 MFMA.  XCD-swizzled; rel from
// precomputed bf16 relb (8 KB, L2-hot).
// ---------------------------------------------------------------------------
__global__ __launch_bounds__(256) void k_attn(const unsigned short* __restrict__ qkv,
                                              const unsigned short* __restrict__ relb,
                                              unsigned short* __restrict__ aT) {
    int virt = (blockIdx.x & 7) * (B_ * H_ / 8) + (blockIdx.x >> 3);
    int b = virt / H_, h = virt % H_;
    __shared__ unsigned short qt[64][40];      // [t][d] swizzled d-blocks
    __shared__ unsigned short kt[64][40];      // [s][d] swizzled
    __shared__ unsigned short vsm[32][72];     // [d][s]
    __shared__ unsigned short rel[128][40];    // [m][d], row127 = 0
    __shared__ unsigned short wls[64][72];     // softmax weights [t][s]
    __shared__ __half rel_l[64][132];          // rel_logits [t][m]; ao aliased
    unsigned short (*ao)[40] = (unsigned short(*)[40])&rel_l[0][0];

    int tid = threadIdx.x;
    const unsigned short* base = qkv + (size_t)b * (3 * C_) * T_;
    {
        int d = tid >> 3, tg = tid & 7;
        s16x8 qv = *(const s16x8*)(base + (size_t)(h * D_ + d) * T_ + tg * 8);
        s16x8 kv = *(const s16x8*)(base + (size_t)(C_ + h * D_ + d) * T_ + tg * 8);
        s16x8 vv = *(const s16x8*)(base + (size_t)(2 * C_ + h * D_ + d) * T_ + tg * 8);
#pragma unroll
        for (int j = 0; j < 8; ++j) {
            int t = tg * 8 + j;
            int col = (d & 7) | ((((d >> 3) ^ ((t >> 3) & 3)) & 3) << 3);
            qt[t][col] = (unsigned short)qv[j];
            kt[t][col] = (unsigned short)kv[j];
        }
        *(s16x8*)&vsm[d][tg * 8] = vv;
    }
    {
        int m = tid >> 1, hf = tid & 1;
        s16x8* dst = (s16x8*)&rel[m][hf * 16];
        const s16x8* src = (const s16x8*)(relb + m * 32 + hf * 16);
        dst[0] = src[0];
        dst[1] = src[1];
    }
    __syncthreads();

    int wave = tid >> 6, lane = tid & 63;
    int lr = lane & 15, lg = lane >> 4;
    int t0 = wave * 16;
    int tA = t0 + lr;
    s16x8 afq = *(const s16x8*)&qt[tA][((lg ^ ((tA >> 3) & 3)) & 3) << 3];

    // QK^T: 4 N-tiles over s
    f32x4 accS[4];
#pragma unroll
    for (int nt = 0; nt < 4; ++nt) {
        int s = nt * 16 + lr;
        s16x8 bf = *(const s16x8*)&kt[s][((lg ^ ((s >> 3) & 3)) & 3) << 3];
        f32x4 z = (f32x4){0.f, 0.f, 0.f, 0.f};
        accS[nt] = __builtin_amdgcn_mfma_f32_16x16x32_bf16(afq, bf, z, 0, 0, 0);
    }
    // rel logits: 8 N-tiles over m -> rel_l (fp16)
#pragma unroll
    for (int mt = 0; mt < 8; ++mt) {
        int m = mt * 16 + lr;
        s16x8 bf = *(const s16x8*)&rel[m][lg * 8];
        f32x4 z = (f32x4){0.f, 0.f, 0.f, 0.f};
        f32x4 rr = __builtin_amdgcn_mfma_f32_16x16x32_bf16(afq, bf, z, 0, 0, 0);
#pragma unroll
        for (int r2 = 0; r2 < 4; ++r2)
            rel_l[t0 + lg * 4 + r2][mt * 16 + lr] = __float2half(rr[r2]);
    }
    __syncthreads();

    // softmax (fp32): lane owns 4 rows (t0+lg*4+r2) x 4 cols (nt*16+lr)
    float vals[4][4], mx[4], inv[4];
#pragma unroll
    for (int r2 = 0; r2 < 4; ++r2) {
        int t = t0 + lg * 4 + r2;
        float m0 = -1e30f;
#pragma unroll
        for (int nt = 0; nt < 4; ++nt) {
            int s = nt * 16 + lr;
            float v = accS[nt][r2] + __half2float(rel_l[t][s - t + 63]);
            vals[nt][r2] = v;
            m0 = fmaxf(m0, v);
        }
        m0 = fmaxf(m0, __shfl_xor(m0, 1));
        m0 = fmaxf(m0, __shfl_xor(m0, 2));
        m0 = fmaxf(m0, __shfl_xor(m0, 4));
        m0 = fmaxf(m0, __shfl_xor(m0, 8));
        mx[r2] = m0;
    }
#pragma unroll
    for (int r2 = 0; r2 < 4; ++r2) {
        float s0 = 0.f;
#pragma unroll
        for (int nt = 0; nt < 4; ++nt) {
            float e = __expf(vals[nt][r2] - mx[r2]);
            vals[nt][r2] = e;
            s0 += e;
        }
        s0 += __shfl_xor(s0, 1);
        s0 += __shfl_xor(s0, 2);
        s0 += __shfl_xor(s0, 4);
        s0 += __shfl_xor(s0, 8);
        inv[r2] = 1.0f / s0;
    }
#pragma unroll
    for (int r2 = 0; r2 < 4; ++r2) {
        int t = t0 + lg * 4 + r2;
#pragma unroll
        for (int nt = 0; nt < 4; ++nt)
            wls[t][nt * 16 + lr] = f2bf(vals[nt][r2] * inv[r2]);
    }
    __syncthreads();   // wls ready; also fences rel_l reads before ao overwrite

    // PV: attn[t][dd] = sum_s w[t][s] * v[dd][s]
    f32x4 accO[2];
    accO[0] = (f32x4){0.f, 0.f, 0.f, 0.f};
    accO[1] = (f32x4){0.f, 0.f, 0.f, 0.f};
#pragma unroll
    for (int ks = 0; ks < 2; ++ks) {
        s16x8 pa = *(const s16x8*)&wls[tA][ks * 32 + lg * 8];
#pragma unroll
        for (int nt = 0; nt < 2; ++nt) {
            s16x8 bf = *(const s16x8*)&vsm[nt * 16 + lr][ks * 32 + lg * 8];
            accO[nt] = __builtin_amdgcn_mfma_f32_16x16x32_bf16(pa, bf, accO[nt], 0, 0, 0);
        }
    }
#pragma unroll
    for (int nt = 0; nt < 2; ++nt)
#pragma unroll
        for (int r2 = 0; r2 < 4; ++r2)
            ao[t0 + lg * 4 + r2][nt * 16 + lr] = f2bf(accO[nt][r2]);
    __syncthreads();

    // scrambled write: aT[b][tout][h*32+qr] = ao[tA][dA]
    unsigned short* dstb = aT + (size_t)b * T_ * C_ + h * D_;
#pragma unroll
    for (int it = 0; it < 8; ++it) {
        int idx = it * 256 + tid;
        int qr = idx & 31, tout = idx >> 5;
        int ii = tout & 31;
        int j = 2 * qr + (tout >> 5);
        int tAo = 2 * ii + (j >> 5);
        int dA = j & 31;
        dstb[(size_t)tout * C_ + qr] = ao[tAo][dA];
    }
}

// ---------------------------------------------------------------------------
// Kernel 4: out GEMM (bf16 MFMA), writes final (N,C,T,V) fp32. XCD-swizzled.
// ---------------------------------------------------------------------------
__global__ __launch_bounds__(256) void k_out(const unsigned short* __restrict__ Wb,
                                             const float* __restrict__ bias,
                                             const unsigned short* __restrict__ aT,
                                             float* __restrict__ out) {
    int virt = (blockIdx.x & 7) * (768 / 8) + (blockIdx.x >> 3);
    int n = virt / 12, r = virt % 12, mo = r >> 2, tc = r & 3;
    __shared__ unsigned short Bs[400][40];     // [col][k], 32KB
    int tid = threadIdx.x;
    int wave = tid >> 6, lane = tid & 63;
    int lr = lane & 15, lg = lane >> 4;

    f32x4 acc[25];
#pragma unroll
    for (int j = 0; j < 25; ++j) acc[j] = (f32x4){0.f, 0.f, 0.f, 0.f};

    const unsigned short* arow = Wb + (size_t)(mo * 64 + wave * 16 + lr) * C_ + lg * 8;

    for (int k0 = 0; k0 < C_; k0 += 32) {
        __syncthreads();
        for (int col = tid; col < 400; col += 256) {
            int tl = (col * 41) >> 10;         // col/25 (exact for col<624)
            int v = col - tl * 25;
            const s16x8* src = (const s16x8*)(aT +
                ((size_t)(n * V_ + v) * T_ + tc * 16 + tl) * C_ + k0);
            s16x8* dst = (s16x8*)&Bs[col][0];
            dst[0] = src[0]; dst[1] = src[1]; dst[2] = src[2]; dst[3] = src[3];
        }
        __syncthreads();
        s16x8 a = *(const s16x8*)(arow + k0);
#pragma unroll
        for (int j = 0; j < 25; ++j) {
            s16x8 bf = *(const s16x8*)&Bs[j * 16 + lr][lg * 8];
            acc[j] = __builtin_amdgcn_mfma_f32_16x16x32_bf16(a, bf, acc[j], 0, 0, 0);
        }
    }
#pragma unroll
    for (int j = 0; j < 25; ++j) {
        int c = j * 16 + lr;
        int tl = (c * 41) >> 10;
        int v = c - tl * 25;
        int t = tc * 16 + tl;
#pragma unroll
        for (int r2 = 0; r2 < 4; ++r2) {
            int o = mo * 64 + wave * 16 + lg * 4 + r2;
            out[(((size_t)n * C_ + o) * T_ + t) * V_ + v] = acc[j][r2] + bias[o];
        }
    }
}

// ---------------------------------------------------------------------------
extern "C" void kernel_launch(void* const* d_in, const int* in_sizes, int n_in,
                              void* d_out, int out_size, void* d_ws, size_t ws_size,
                              hipStream_t stream) {
    const float* x       = (const float*)d_in[0];
    const float* w_qkv   = (const float*)d_in[1];
    const float* b_qkv   = (const float*)d_in[2];
    const float* w_out   = (const float*)d_in[3];
    const float* b_out   = (const float*)d_in[4];
    const float* rel_emb = (const float*)d_in[5];
    float* out = (float*)d_out;

    // workspace (ushorts): xt | qkv | aT | wqb | wob | relb  (~197 MB)
    unsigned short* xt   = (unsigned short*)d_ws;
    unsigned short* qkvb = xt + (size_t)B_ * T_ * C_;
    unsigned short* aTb  = qkvb + (size_t)B_ * 3 * C_ * T_;
    unsigned short* wqb  = aTb + (size_t)B_ * T_ * C_;
    unsigned short* wob  = wqb + (size_t)NQ_;
    unsigned short* relb = wob + (size_t)NO_;

    k_wconv<<<592, 256, 0, stream>>>(w_qkv, w_out, rel_emb, wqb, wob, relb);
    k_xpose<<<768, 256, 0, stream>>>(x, xt);
    k_qkv<<<B_ * 9, 256, 0, stream>>>(wqb, b_qkv, xt, qkvb);
    k_attn<<<B_ * H_, 256, 0, stream>>>(qkvb, relb, aTb);
    k_out<<<768, 256, 0, stream>>>(wob, b_out, aTb, out);
}